// Round 1
// baseline (94.698 us; speedup 1.0000x reference)
//
#include <hip/hip_runtime.h>

// Problem constants (from reference):
//   OUT=8192, GROUPS=64, GROUP_SIZE=128 -> weight flat: 8192*64*64 int32 (each
//   holds one byte = two int4 nibbles), scale flat: 8192*64 f32, out: 8192*8192 f32.
#define NW_TOTAL 33554432LL   // 8192*64*64 packed int32 elements
#define N_QUADS  (NW_TOTAL / 4)

__global__ __launch_bounds__(256)
void PackedINTSymmetricWeightsDecompressor_74440373174409_kernel(
        const int* __restrict__ w,
        const float* __restrict__ s,
        float* __restrict__ out)
{
    const long long stride = (long long)gridDim.x * blockDim.x;
    for (long long t = (long long)blockIdx.x * blockDim.x + threadIdx.x;
         t < N_QUADS; t += stride) {
        const long long base = t * 4;                 // index into packed int32 weights
        const int4 wv = *reinterpret_cast<const int4*>(w + base);
        // group flat index = (weight flat index) / 64; scale is [OUT][GROUPS][1]
        const float sc = s[base >> 6];

        float4 a, b;
        a.x = (float)(( wv.x        & 0xF) - 8) * sc;
        a.y = (float)(((wv.x >> 4)  & 0xF) - 8) * sc;
        a.z = (float)(( wv.y        & 0xF) - 8) * sc;
        a.w = (float)(((wv.y >> 4)  & 0xF) - 8) * sc;
        b.x = (float)(( wv.z        & 0xF) - 8) * sc;
        b.y = (float)(((wv.z >> 4)  & 0xF) - 8) * sc;
        b.z = (float)(( wv.w        & 0xF) - 8) * sc;
        b.w = (float)(((wv.w >> 4)  & 0xF) - 8) * sc;

        float4* op = reinterpret_cast<float4*>(out + base * 2);
        op[0] = a;
        op[1] = b;
    }
}

extern "C" void kernel_launch(void* const* d_in, const int* in_sizes, int n_in,
                              void* d_out, int out_size, void* d_ws, size_t ws_size,
                              hipStream_t stream) {
    const int*   w   = (const int*)d_in[0];
    const float* s   = (const float*)d_in[1];
    float*       out = (float*)d_out;

    // Memory-bound: cap grid at ~2048 blocks, grid-stride the rest (16 iters/thread).
    const int block = 256;
    const int grid  = 2048;
    PackedINTSymmetricWeightsDecompressor_74440373174409_kernel<<<grid, block, 0, stream>>>(w, s, out);
}